// Round 1
// baseline (4574.644 us; speedup 1.0000x reference)
//
#include <hip/hip_runtime.h>

// RNN: S=512, B=128, I=256, H=512, O=128
// Phase 1: xh = x @ W_xh + b_h         -> bf16 in ws   (parallel GEMM)
// Phase 2: h_t = tanh(xh_t + h @ W_hh); out_t = h_t @ W_hy + b_y
//          8 workgroups (16 batch rows each), 512 sequential steps,
//          h kept in LDS, W read from L2 in MFMA-B-fragment-packed layout.
//          Output GEMM fused into the same K-loop (reads h_{t-1} from LDS
//          before it is overwritten) -> hs never materialized.

typedef __attribute__((ext_vector_type(8))) short short8;   // 8 bf16 = 4 VGPRs
typedef __attribute__((ext_vector_type(4))) float f32x4;    // MFMA C/D

__device__ __forceinline__ unsigned short f32_to_bf16(float f) {
  unsigned int u = __float_as_uint(f);
  u += 0x7FFFu + ((u >> 16) & 1u);          // round-to-nearest-even
  return (unsigned short)(u >> 16);
}
__device__ __forceinline__ float bf16_to_f32(unsigned short h) {
  return __uint_as_float(((unsigned int)h) << 16);
}
__device__ __forceinline__ float fast_tanh(float x) {
  float e = __expf(2.0f * x);               // inf-safe: x>>0 -> 1, x<<0 -> -1
  return 1.0f - 2.0f / (e + 1.0f);
}

// ---------------------------------------------------------------------------
// Pack a K x N fp32 row-major matrix into bf16 B-fragment tiles for
// mfma_f32_16x16x32_bf16.  Tile (nt, kt): lane holds B[k=kt*32+(lane>>4)*8+j]
// [n=nt*16+(lane&15)], j=0..7, stored contiguously: P[tile*512 + lane*8 + j].
// tile = nt * (K/32) + kt.
// ---------------------------------------------------------------------------
__global__ void pack_b_kernel(const float* __restrict__ W,
                              unsigned short* __restrict__ P, int K, int N) {
  int tid  = blockIdx.x * 256 + threadIdx.x;
  int lane = tid & 63;
  int tile = tid >> 6;
  int nKt  = K >> 5;
  int nTiles = (N >> 4) * nKt;
  if (tile >= nTiles) return;
  int nt = tile / nKt;
  int kt = tile - nt * nKt;
  int n  = (nt << 4) + (lane & 15);
  int k0 = (kt << 5) + ((lane >> 4) << 3);
  unsigned short* dst = P + (size_t)tile * 512 + lane * 8;
#pragma unroll
  for (int j = 0; j < 8; ++j)
    dst[j] = f32_to_bf16(W[(size_t)(k0 + j) * N + n]);
}

// ---------------------------------------------------------------------------
// Phase 1: xh[M=65536, N=512] = x[M, K=256] @ W_xh + b_h   (bf16 out)
// Block 256 (4 waves), tile 64x64, K staged whole in LDS as bf16.
// ---------------------------------------------------------------------------
__global__ __launch_bounds__(256) void xh_gemm_kernel(
    const float* __restrict__ x, const unsigned short* __restrict__ Wxh_p,
    const float* __restrict__ b_h, unsigned short* __restrict__ xh) {
  __shared__ __align__(16) unsigned short Abuf[64 * 264];  // 64 rows, pad +8
  const int tid = threadIdx.x;
  const int m0 = blockIdx.x * 64;
  const int n0 = blockIdx.y * 64;

  // Stage A (64x256 fp32 -> bf16 LDS), fully coalesced 4KB per iteration.
#pragma unroll
  for (int i = 0; i < 16; ++i) {
    int flat = i * 1024 + tid * 4;           // float index in 64x256 tile
    int row = flat >> 8, col = flat & 255;
    float4 v = *(const float4*)(x + (size_t)(m0 + row) * 256 + col);
    ushort4 u;
    u.x = f32_to_bf16(v.x); u.y = f32_to_bf16(v.y);
    u.z = f32_to_bf16(v.z); u.w = f32_to_bf16(v.w);
    *(ushort4*)(Abuf + row * 264 + col) = u;
  }
  __syncthreads();

  const int w = tid >> 6, lane = tid & 63;
  const int quad = lane >> 4, col16 = lane & 15;
  f32x4 acc[4] = {{0.f,0.f,0.f,0.f},{0.f,0.f,0.f,0.f},
                  {0.f,0.f,0.f,0.f},{0.f,0.f,0.f,0.f}};
  const int aBase = (w * 16 + col16) * 264 + quad * 8;   // ushort index
#pragma unroll
  for (int kt = 0; kt < 8; ++kt) {
    short8 a = *(const short8*)(Abuf + aBase + kt * 32);
#pragma unroll
    for (int nt = 0; nt < 4; ++nt) {
      int tile = (blockIdx.y * 4 + nt) * 8 + kt;         // nKt = 256/32 = 8
      short8 b = *(const short8*)(Wxh_p + (size_t)tile * 512 + lane * 8);
      acc[nt] = __builtin_amdgcn_mfma_f32_16x16x32_bf16(a, b, acc[nt], 0, 0, 0);
    }
  }
#pragma unroll
  for (int nt = 0; nt < 4; ++nt) {
    int n = n0 + nt * 16 + col16;
    float bh = b_h[n];
#pragma unroll
    for (int r = 0; r < 4; ++r) {
      int m = m0 + w * 16 + quad * 4 + r;    // C/D: col=lane&15, row=quad*4+r
      xh[(size_t)m * 512 + n] = f32_to_bf16(acc[nt][r] + bh);
    }
  }
}

// ---------------------------------------------------------------------------
// Phase 2: sequential recurrence + fused output GEMM.
// Grid 8, block 1024 (16 waves). wg handles batch rows [b0, b0+16).
// Wave w: main GEMM ntiles {2w, 2w+1} (cols 32w..32w+31 of H=512);
// waves 0..7 additionally accumulate O-ntile w (cols 16w..16w+15 of O=128)
// from the SAME LDS h_{t-1} in the same K-loop -> out[t-1].
// ---------------------------------------------------------------------------
__global__ __launch_bounds__(1024) void rnn_recurrence_kernel(
    const unsigned short* __restrict__ xh,      // [S*B, 512] bf16
    const unsigned short* __restrict__ Whh_p,   // packed, nKt=16, ntg 0..31
    const unsigned short* __restrict__ Why_p,   // packed, nKt=16, ntg 0..7
    const float* __restrict__ b_y,
    float* __restrict__ out) {                  // [S, B, 128] fp32
  __shared__ __align__(16) unsigned short Hbuf[16 * 520];  // pad 512 -> 520
  const int tid = threadIdx.x;
  const int w = tid >> 6, lane = tid & 63;
  const int quad = lane >> 4, col16 = lane & 15;
  const int b0 = blockIdx.x * 16;
  const bool doO = (w < 8);
  const float by_v = doO ? b_y[w * 16 + col16] : 0.f;

  for (int i = tid; i < 16 * 520; i += 1024) Hbuf[i] = 0;  // h_{-1} = 0
  __syncthreads();

  const int aBase = col16 * 520 + quad * 8;   // A: m=lane&15, k=quad*8+j
  const unsigned short* whh0 = Whh_p + (size_t)(2 * w) * 16 * 512 + lane * 8;
  const unsigned short* whh1 = Whh_p + (size_t)(2 * w + 1) * 16 * 512 + lane * 8;
  const unsigned short* why  = Why_p + (size_t)w * 16 * 512 + lane * 8;

  for (int t = 0; t < 512; ++t) {
    // xh for this step (consumed after the barrier; loads overlap MFMAs)
    float xh_v0[4], xh_v1[4];
    {
      const unsigned short* xp =
          xh + ((size_t)t * 128 + b0 + quad * 4) * 512 + w * 32 + col16;
#pragma unroll
      for (int r = 0; r < 4; ++r) {
        xh_v0[r] = bf16_to_f32(xp[r * 512]);
        xh_v1[r] = bf16_to_f32(xp[r * 512 + 16]);
      }
    }
    f32x4 acc0 = {0.f,0.f,0.f,0.f}, acc1 = {0.f,0.f,0.f,0.f};
    f32x4 oacc = {0.f,0.f,0.f,0.f};
#pragma unroll
    for (int kt = 0; kt < 16; ++kt) {
      short8 a  = *(const short8*)(Hbuf + aBase + kt * 32);
      short8 bA = *(const short8*)(whh0 + (size_t)kt * 512);
      short8 bB = *(const short8*)(whh1 + (size_t)kt * 512);
      acc0 = __builtin_amdgcn_mfma_f32_16x16x32_bf16(a, bA, acc0, 0, 0, 0);
      acc1 = __builtin_amdgcn_mfma_f32_16x16x32_bf16(a, bB, acc1, 0, 0, 0);
      if (doO) {
        short8 bO = *(const short8*)(why + (size_t)kt * 512);
        oacc = __builtin_amdgcn_mfma_f32_16x16x32_bf16(a, bO, oacc, 0, 0, 0);
      }
    }
    __syncthreads();   // all reads of h_{t-1} complete

    // h_t = tanh(xh_t + h_{t-1} @ W_hh); write into Hbuf
#pragma unroll
    for (int r = 0; r < 4; ++r) {
      float h0 = fast_tanh(acc0[r] + xh_v0[r]);
      float h1 = fast_tanh(acc1[r] + xh_v1[r]);
      int row = quad * 4 + r;
      Hbuf[row * 520 + w * 32 + col16]      = f32_to_bf16(h0);
      Hbuf[row * 520 + w * 32 + 16 + col16] = f32_to_bf16(h1);
    }
    // oacc = h_{t-1} @ W_hy -> out[t-1]  (t=0 slot is h_{-1}=0: skip)
    if (doO && t > 0) {
#pragma unroll
      for (int r = 0; r < 4; ++r)
        out[((size_t)(t - 1) * 128 + b0 + quad * 4 + r) * 128 + w * 16 + col16] =
            oacc[r] + by_v;
    }
    __syncthreads();   // h_t visible before next step's reads
  }

  // Epilogue: out[511] from h_511
  if (doO) {
    f32x4 oacc = {0.f,0.f,0.f,0.f};
#pragma unroll
    for (int kt = 0; kt < 16; ++kt) {
      short8 a  = *(const short8*)(Hbuf + aBase + kt * 32);
      short8 bO = *(const short8*)(why + (size_t)kt * 512);
      oacc = __builtin_amdgcn_mfma_f32_16x16x32_bf16(a, bO, oacc, 0, 0, 0);
    }
#pragma unroll
    for (int r = 0; r < 4; ++r)
      out[((size_t)511 * 128 + b0 + quad * 4 + r) * 128 + w * 16 + col16] =
          oacc[r] + by_v;
  }
}

// ---------------------------------------------------------------------------
extern "C" void kernel_launch(void* const* d_in, const int* in_sizes, int n_in,
                              void* d_out, int out_size, void* d_ws, size_t ws_size,
                              hipStream_t stream) {
  const float* x    = (const float*)d_in[0];   // [512,128,256]
  const float* W_xh = (const float*)d_in[1];   // [256,512]
  const float* W_hh = (const float*)d_in[2];   // [512,512]
  const float* W_hy = (const float*)d_in[3];   // [512,128]
  const float* b_h  = (const float*)d_in[4];   // [512]
  const float* b_y  = (const float*)d_in[5];   // [128]
  float* out = (float*)d_out;                  // [512,128,128]

  // ws layout (needs ~68.2 MB):
  char* ws = (char*)d_ws;
  unsigned short* Wxh_p = (unsigned short*)(ws);                    // 256 KB
  unsigned short* Whh_p = (unsigned short*)(ws + (256 << 10));      // 512 KB
  unsigned short* Why_p = (unsigned short*)(ws + (768 << 10));      // 128 KB
  unsigned short* xh    = (unsigned short*)(ws + (1024 << 10));     // 64 MB

  // Repack weights to bf16 B-fragment layout.
  pack_b_kernel<<<64, 256, 0, stream>>>(W_xh, Wxh_p, 256, 512);   // 256 tiles
  pack_b_kernel<<<128, 256, 0, stream>>>(W_hh, Whh_p, 512, 512);  // 512 tiles
  pack_b_kernel<<<32, 256, 0, stream>>>(W_hy, Why_p, 512, 128);   // 128 tiles

  // Phase 1: xh = x @ W_xh + b_h
  dim3 g1(1024, 8);
  xh_gemm_kernel<<<g1, 256, 0, stream>>>(x, Wxh_p, b_h, xh);

  // Phase 2: recurrence + fused output projection
  rnn_recurrence_kernel<<<8, 1024, 0, stream>>>(xh, Whh_p, Why_p, b_y, out);
}

// Round 2
// 2577.538 us; speedup vs baseline: 1.7748x; 1.7748x over previous
//
#include <hip/hip_runtime.h>

// RNN: S=512, B=128, I=256, H=512, O=128
// R2 design: weight-resident recurrence.
//  k1 pack_b x3 : repack weights to bf16 MFMA-B-fragment tiles
//  k2 xh_gemm   : xh = x@W_xh + b_h, stored PRE-SWIZZLED per recurrence
//                 consumer thread (4 contiguous dwordx4 per thread per step)
//  k3 rnn       : 8 wgs x 256 thr (1 wave/SIMD, 512-VGPR budget). W_hh held
//                 88 frags/wave in VGPR + 31 frags/wave in LDS + 9 streamed
//                 from L2 per step. Double-buffered h in LDS, 1 barrier/step.
//                 Writes hs (bf16) in-place over consumed xh windows.
//  k4 out_gemm  : out = hs@W_hy + b_y across all CUs.

typedef __attribute__((ext_vector_type(8))) short short8;   // 8 bf16
typedef __attribute__((ext_vector_type(4))) float f32x4;    // MFMA C/D

__device__ __forceinline__ unsigned short f32_to_bf16(float f) {
  unsigned int u = __float_as_uint(f);
  u += 0x7FFFu + ((u >> 16) & 1u);
  return (unsigned short)(u >> 16);
}
__device__ __forceinline__ float fast_tanh(float x) {
  float e = __expf(2.0f * x);
  return 1.0f - 2.0f / (e + 1.0f);
}

// ---------------------------------------------------------------------------
// Pack K x N fp32 row-major -> bf16 B-fragment tiles (16x16x32 MFMA).
// Tile (nt,kt): lane holds B[k=kt*32+(lane>>4)*8+j][n=nt*16+(lane&15)],
// stored P[tile*512 + lane*8 + j], tile = nt*(K/32)+kt.
// ---------------------------------------------------------------------------
__global__ void pack_b_kernel(const float* __restrict__ W,
                              unsigned short* __restrict__ P, int K, int N) {
  int tid  = blockIdx.x * 256 + threadIdx.x;
  int lane = tid & 63;
  int tile = tid >> 6;
  int nKt  = K >> 5;
  int nTiles = (N >> 4) * nKt;
  if (tile >= nTiles) return;
  int nt = tile / nKt;
  int kt = tile - nt * nKt;
  int n  = (nt << 4) + (lane & 15);
  int k0 = (kt << 5) + ((lane >> 4) << 3);
  unsigned short* dst = P + (size_t)tile * 512 + lane * 8;
#pragma unroll
  for (int j = 0; j < 8; ++j)
    dst[j] = f32_to_bf16(W[(size_t)(k0 + j) * N + n]);
}

// ---------------------------------------------------------------------------
// Phase 1: xh = x@W_xh + b_h, stored swizzled:
// xh_s[((t*8+g)*4 + ws)*2048 + lane*32 + (nt*4+r)] =
//   xh[t][g*16 + (lane>>4)*4 + r][ws*128 + nt*16 + (lane&15)]
// Block 256 (4 waves), tile 64 rows x 128 cols. grid (1024, 4).
// ---------------------------------------------------------------------------
__global__ __launch_bounds__(256) void xh_gemm_kernel(
    const float* __restrict__ x, const unsigned short* __restrict__ Wxh_p,
    const float* __restrict__ b_h, unsigned short* __restrict__ xh_s) {
  __shared__ __align__(16) unsigned short Abuf[64 * 264];
  const int tid = threadIdx.x;
  const int m0 = blockIdx.x * 64;
  const int by = blockIdx.y;                  // n0 = by*128

  // Stage A tile (64x256 fp32 -> bf16), coalesced.
#pragma unroll
  for (int i = 0; i < 16; ++i) {
    int flat = i * 1024 + tid * 4;
    int row = flat >> 8, col = flat & 255;
    float4 v = *(const float4*)(x + (size_t)(m0 + row) * 256 + col);
    ushort4 u;
    u.x = f32_to_bf16(v.x); u.y = f32_to_bf16(v.y);
    u.z = f32_to_bf16(v.z); u.w = f32_to_bf16(v.w);
    *(ushort4*)(Abuf + row * 264 + col) = u;
  }
  __syncthreads();

  const int w = tid >> 6, lane = tid & 63;
  const int quad = lane >> 4, col16 = lane & 15;
  f32x4 acc[8];
#pragma unroll
  for (int nt = 0; nt < 8; ++nt) acc[nt] = (f32x4){0.f,0.f,0.f,0.f};
  const int aBase = (w * 16 + col16) * 264 + quad * 8;
#pragma unroll
  for (int kt = 0; kt < 8; ++kt) {
    short8 a = *(const short8*)(Abuf + aBase + kt * 32);
#pragma unroll
    for (int nt = 0; nt < 8; ++nt) {
      int tile = (by * 8 + nt) * 8 + kt;      // nKt(Wxh)=8
      short8 b = *(const short8*)(Wxh_p + (size_t)tile * 512 + lane * 8);
      acc[nt] = __builtin_amdgcn_mfma_f32_16x16x32_bf16(a, b, acc[nt], 0, 0, 0);
    }
  }
  // Epilogue: pack 32 bf16 per thread, 4 coalesced dwordx4 stores.
  const int t = (m0 + w * 16) >> 7;
  const int g = ((m0 + w * 16) & 127) >> 4;
  unsigned short hv[32];
#pragma unroll
  for (int nt = 0; nt < 8; ++nt) {
    float bh = b_h[by * 128 + nt * 16 + col16];
#pragma unroll
    for (int r = 0; r < 4; ++r)
      hv[nt * 4 + r] = f32_to_bf16(acc[nt][r] + bh);
  }
  unsigned short* dst = xh_s + ((size_t)(t * 8 + g) * 4 + by) * 2048 + lane * 32;
#pragma unroll
  for (int k = 0; k < 4; ++k) {
    uint4 u;
    u.x = (unsigned)hv[k*8+0] | ((unsigned)hv[k*8+1] << 16);
    u.y = (unsigned)hv[k*8+2] | ((unsigned)hv[k*8+3] << 16);
    u.z = (unsigned)hv[k*8+4] | ((unsigned)hv[k*8+5] << 16);
    u.w = (unsigned)hv[k*8+6] | ((unsigned)hv[k*8+7] << 16);
    *(uint4*)(dst + k * 8) = u;
  }
}

// ---------------------------------------------------------------------------
// Phase 2: recurrence. grid 8, block 256 (4 waves, 1 wave/SIMD, <=512 VGPR).
// Wave w owns hidden cols [w*128, w*128+128): 8 ntiles x 16 kt = 128 B-frags:
//   kt 0..10        -> VGPR-resident (88 frags, 352 regs)
//   kt 11..13, 14(nt<7) -> LDS-resident (31 frags, 127KB total)
//   kt 14(nt=7), 15 -> streamed from L2 each step (9 frags)
// h double-buffered in LDS; 1 barrier/step. hs written over consumed xh.
// ---------------------------------------------------------------------------
__global__ __launch_bounds__(256, 1) void rnn_recurrence_kernel(
    const unsigned short* __restrict__ Whh_p,
    unsigned short* __restrict__ xhs) {          // xh_s in, hs out (in-place)
  __shared__ __align__(16) unsigned short Hb[2][16 * 520];   // 33,280 B
  __shared__ __align__(16) unsigned short Wl[4][31 * 512];   // 126,976 B
  const int tid = threadIdx.x;
  const int w = tid >> 6, lane = tid & 63;
  const int quad = lane >> 4, col16 = lane & 15;
  const int g = blockIdx.x;

  // h_{-1} = 0
  for (int i = tid; i < 2 * 16 * 520; i += 256) (&Hb[0][0])[i] = 0;

  // VGPR-resident fragments: kt 0..10 for each of 8 ntiles.
  short8 wf[88];
#pragma unroll
  for (int nt = 0; nt < 8; ++nt)
#pragma unroll
    for (int kt = 0; kt <= 10; ++kt)
      wf[nt * 11 + kt] = *(const short8*)(
          Whh_p + ((size_t)((w * 8 + nt) * 16 + kt)) * 512 + lane * 8);

  // LDS-resident fragments.
  unsigned short* wlw = Wl[w];
#pragma unroll
  for (int idx = 0; idx < 31; ++idx) {
    int kt = (idx < 24) ? (11 + (idx >> 3)) : 14;
    int nt = (idx < 24) ? (idx & 7) : (idx - 24);
    short8 v = *(const short8*)(
        Whh_p + ((size_t)((w * 8 + nt) * 16 + kt)) * 512 + lane * 8);
    *(short8*)(wlw + idx * 512 + lane * 8) = v;
  }
  __syncthreads();

  const unsigned short* wlwL = wlw + lane * 8;
  const int aOff = col16 * 520 + quad * 8;          // A-frag base in Hb row
  // hs store mapping (contiguous re-read of h rows)
  const int hrow = tid >> 4, hcol = (tid & 15) * 32;
  const int rbOff = hrow * 520 + hcol;
  unsigned short* hsW = xhs + (size_t)g * 8192 + hrow * 512 + hcol;
  const unsigned short* xhL = xhs + (size_t)g * 8192 + (size_t)w * 2048 + lane * 32;
  const unsigned short* wstream = Whh_p + lane * 8;  // + tile*512 offsets

#pragma unroll 1
  for (int t = 0; t < 512; ++t) {
    const unsigned short* rb = Hb[t & 1];
    unsigned short* wb = Hb[(t & 1) ^ 1];

    // Launder streamed-weight base so loads are not hoisted out of the loop.
    unsigned long long up = (unsigned long long)wstream;
    asm volatile("" : "+v"(up));
    const unsigned short* pS = (const unsigned short*)up;

    // Streamed fragments (L2-resident): kt14 nt7 + kt15 nt0..7.
    short8 s14_7 = *(const short8*)(pS + ((size_t)((w * 8 + 7) * 16 + 14)) * 512);
    short8 s15[8];
#pragma unroll
    for (int nt = 0; nt < 8; ++nt)
      s15[nt] = *(const short8*)(pS + ((size_t)((w * 8 + nt) * 16 + 15)) * 512);

    // hs store of h_{t-1} (window == consumed xh[t-1] window).
    if (t > 0) {
#pragma unroll
      for (int k = 0; k < 4; ++k) {
        short8 v = *(const short8*)(rb + rbOff + k * 8);
        *(short8*)(hsW + (size_t)(t - 1) * 65536 + k * 8) = v;
      }
    }

    // xh for this step: 4 coalesced dwordx4.
    uint4 xq0 = *(const uint4*)(xhL + (size_t)t * 65536);
    uint4 xq1 = *(const uint4*)(xhL + (size_t)t * 65536 + 8);
    uint4 xq2 = *(const uint4*)(xhL + (size_t)t * 65536 + 16);
    uint4 xq3 = *(const uint4*)(xhL + (size_t)t * 65536 + 24);

    f32x4 acc[8];
#pragma unroll
    for (int nt = 0; nt < 8; ++nt) acc[nt] = (f32x4){0.f,0.f,0.f,0.f};

#pragma unroll
    for (int kt = 0; kt < 16; ++kt) {
      short8 a = *(const short8*)(rb + aOff + kt * 32);
#pragma unroll
      for (int nt = 0; nt < 8; ++nt) {
        short8 b;
        if (kt <= 10)       b = wf[nt * 11 + kt];
        else if (kt <= 13)  b = *(const short8*)(wlwL + ((kt - 11) * 8 + nt) * 512);
        else if (kt == 14)  b = (nt < 7) ? *(const short8*)(wlwL + (24 + nt) * 512)
                                         : s14_7;
        else                b = s15[nt];
        acc[nt] = __builtin_amdgcn_mfma_f32_16x16x32_bf16(a, b, acc[nt], 0, 0, 0);
      }
    }

    // Epilogue: h_t = tanh(xh_t + h_{t-1}@W_hh) -> wb.
    unsigned xw[16] = {xq0.x, xq0.y, xq0.z, xq0.w, xq1.x, xq1.y, xq1.z, xq1.w,
                       xq2.x, xq2.y, xq2.z, xq2.w, xq3.x, xq3.y, xq3.z, xq3.w};
#pragma unroll
    for (int nt = 0; nt < 8; ++nt) {
#pragma unroll
      for (int r = 0; r < 4; ++r) {
        int j = nt * 4 + r;
        unsigned uu = xw[j >> 1];
        float xv = (j & 1) ? __uint_as_float(uu & 0xFFFF0000u)
                           : __uint_as_float(uu << 16);
        float h = fast_tanh(acc[nt][r] + xv);
        wb[(quad * 4 + r) * 520 + w * 128 + nt * 16 + col16] = f32_to_bf16(h);
      }
    }
    __syncthreads();
  }

  // Final hs store: h_511 lives in Hb[0] (t=512 view).
  {
    const unsigned short* rb = Hb[0];
#pragma unroll
    for (int k = 0; k < 4; ++k) {
      short8 v = *(const short8*)(rb + rbOff + k * 8);
      *(short8*)(hsW + (size_t)511 * 65536 + k * 8) = v;
    }
  }
}

// ---------------------------------------------------------------------------
// Phase 3: out = hs @ W_hy + b_y.  [65536,512]@[512,128] fp32 out.
// Block 256 (4 waves), 64 rows/block, all 128 cols. A read direct from global.
// ---------------------------------------------------------------------------
__global__ __launch_bounds__(256) void out_gemm_kernel(
    const unsigned short* __restrict__ hs, const unsigned short* __restrict__ Why_p,
    const float* __restrict__ b_y, float* __restrict__ out) {
  const int tid = threadIdx.x;
  const int w = tid >> 6, lane = tid & 63;
  const int quad = lane >> 4, col16 = lane & 15;
  const int m0 = blockIdx.x * 64 + w * 16;

  f32x4 acc[8];
#pragma unroll
  for (int nt = 0; nt < 8; ++nt) acc[nt] = (f32x4){0.f,0.f,0.f,0.f};

  const unsigned short* aP = hs + (size_t)(m0 + col16) * 512 + quad * 8;
#pragma unroll
  for (int kt = 0; kt < 16; ++kt) {
    short8 a = *(const short8*)(aP + kt * 32);
#pragma unroll
    for (int nt = 0; nt < 8; ++nt) {
      int tile = nt * 16 + kt;                 // nKt(Why)=16
      short8 b = *(const short8*)(Why_p + (size_t)tile * 512 + lane * 8);
      acc[nt] = __builtin_amdgcn_mfma_f32_16x16x32_bf16(a, b, acc[nt], 0, 0, 0);
    }
  }
#pragma unroll
  for (int nt = 0; nt < 8; ++nt) {
    int n = nt * 16 + col16;
    float by = b_y[n];
#pragma unroll
    for (int r = 0; r < 4; ++r)
      out[(size_t)(m0 + quad * 4 + r) * 128 + n] = acc[nt][r] + by;
  }
}

// ---------------------------------------------------------------------------
extern "C" void kernel_launch(void* const* d_in, const int* in_sizes, int n_in,
                              void* d_out, int out_size, void* d_ws, size_t ws_size,
                              hipStream_t stream) {
  const float* x    = (const float*)d_in[0];   // [512,128,256]
  const float* W_xh = (const float*)d_in[1];   // [256,512]
  const float* W_hh = (const float*)d_in[2];   // [512,512]
  const float* W_hy = (const float*)d_in[3];   // [512,128]
  const float* b_h  = (const float*)d_in[4];   // [512]
  const float* b_y  = (const float*)d_in[5];   // [128]
  float* out = (float*)d_out;                  // [512,128,128]

  char* ws = (char*)d_ws;
  unsigned short* Wxh_p = (unsigned short*)(ws);                 // 256 KB
  unsigned short* Whh_p = (unsigned short*)(ws + (256 << 10));   // 512 KB
  unsigned short* Why_p = (unsigned short*)(ws + (768 << 10));   // 128 KB
  unsigned short* xhs   = (unsigned short*)(ws + (1024 << 10));  // 64 MB (xh then hs)

  pack_b_kernel<<<64, 256, 0, stream>>>(W_xh, Wxh_p, 256, 512);
  pack_b_kernel<<<128, 256, 0, stream>>>(W_hh, Whh_p, 512, 512);
  pack_b_kernel<<<32, 256, 0, stream>>>(W_hy, Why_p, 512, 128);

  dim3 g1(1024, 4);
  xh_gemm_kernel<<<g1, 256, 0, stream>>>(x, Wxh_p, b_h, xhs);

  rnn_recurrence_kernel<<<8, 256, 0, stream>>>(Whh_p, xhs);

  out_gemm_kernel<<<1024, 256, 0, stream>>>(xhs, Why_p, b_y, out);
}